// Round 6
// baseline (3276.171 us; speedup 1.0000x reference)
//
#include <hip/hip_runtime.h>

typedef unsigned short u16;
typedef unsigned int   u32;
typedef __bf16  bf16x8 __attribute__((ext_vector_type(8)));
typedef float   f32x4  __attribute__((ext_vector_type(4)));

__device__ __forceinline__ float bf2f(u16 u) {
    u32 v = ((u32)u) << 16;
    return __builtin_bit_cast(float, v);
}
__device__ __forceinline__ u16 f2bf(float f) {
    u32 u = __builtin_bit_cast(u32, f);
    return (u16)((u + 0x7FFFu + ((u >> 16) & 1u)) >> 16);   // RNE
}
__device__ __forceinline__ float ldf(const void* p, long i, int f32) {
    return f32 ? ((const float*)p)[i] : bf2f(((const u16*)p)[i]);
}
// async global->LDS, 16B per lane (LDS dst = wave-uniform base + lane*16)
__device__ __forceinline__ void gl2lds16(const u16* g, u16* l) {
    __builtin_amdgcn_global_load_lds(
        (const __attribute__((address_space(1))) void*)g,
        (__attribute__((address_space(3))) void*)l, 16, 0, 0);
}

// ------------------------------------------------------------- dtype detect
__global__ void detect_dtype(const u32* __restrict__ im, int* __restrict__ flag)
{
    if (blockIdx.x == 0 && threadIdx.x == 0)
        *flag = (im[0] == 0x43E00000u) ? 1 : 0;   // 448.0f fp32 vs packed bf16
}

// ---------------------------------------------------------------- zero (xpad)
__global__ void zero_kernel(uint4* __restrict__ p, const int n)
{
    int i = blockIdx.x * 256 + threadIdx.x;
    if (i < n) p[i] = uint4{0u, 0u, 0u, 0u};
}

// ------------------------------------------------- pad+transpose base_feat
// src: [B=2][C=512][T=16][H=28][W=28] -> xpad: [b][t+1][h+1][w+1][c] bf16
__global__ void pad_fill(const void* __restrict__ src, u16* __restrict__ xpad,
                         const int* __restrict__ flag)
{
    const int f32 = *flag;
    __shared__ u16 lds[56 * 40];
    int blk = blockIdx.x;
    const int h2  = blk % 14;  blk /= 14;
    const int c32 = blk & 15;  blk >>= 4;
    const int t   = blk & 15;
    const int b   = blk >> 4;
    const int tid = threadIdx.x;
    const long sbase = ((long)(b * 512 + c32 * 32) * 16 + t) * 784 + h2 * 56;
    #pragma unroll
    for (int it = tid; it < 1792; it += 256) {
        const int c = it / 56, p = it - c * 56;
        float v = f32 ? ((const float*)src)[sbase + (long)c * 12544 + p]
                      : bf2f(((const u16*)src)[sbase + (long)c * 12544 + p]);
        lds[p * 40 + c] = f2bf(v);
    }
    __syncthreads();
    if (tid < 224) {
        const int p = tid >> 2, g = tid & 3;
        const int h = h2 * 2 + p / 28, w = p % 28;
        const long o = (((long)(b * 18 + t + 1) * 30 + h + 1) * 30 + (w + 1)) * 512
                       + c32 * 32 + g * 8;
        *(uint4*)&xpad[o] = *(const uint4*)&lds[p * 40 + g * 8];
    }
}

// ------------------------------------------------- W_conv [O][I][27] -> Wt[27][O][I]
__global__ void wt_transform(const void* __restrict__ wconv, u16* __restrict__ wt,
                             const int* __restrict__ flag)
{
    const int f32 = *flag;
    __shared__ u16 lds[256 * 28];
    const int tid = threadIdx.x;
    const int pair_base = blockIdx.x * 256;
    const long s0 = (long)pair_base * 27;
    for (int it = tid; it < 256 * 27; it += 256) {
        const int p = it / 27, o = it - p * 27;
        float v = f32 ? ((const float*)wconv)[s0 + it]
                      : bf2f(((const u16*)wconv)[s0 + it]);
        lds[p * 28 + o] = f2bf(v);
    }
    __syncthreads();
    #pragma unroll
    for (int off = 0; off < 27; ++off)
        wt[(long)off * 262144 + pair_base + tid] = lds[tid * 28 + off];
}

// ------------------------------------------------- head weights -> bf16 (merged)
__global__ void cvt_heads(const void* s0, const void* s1, const void* s2,
                          const void* s3, const void* s4,
                          u16* __restrict__ dst, const int* __restrict__ flag)
{
    const int f32 = *flag;
    int i = blockIdx.x * 256 + threadIdx.x;
    if (i >= 1244160) return;
    const void* s; long j;
    if      (i < 15360)   { s = s0; j = i; }
    else if (i < 506880)  { s = s1; j = i - 15360; }
    else if (i < 875520)  { s = s2; j = i - 506880; }
    else if (i < 1121280) { s = s3; j = i - 875520; }
    else                  { s = s4; j = i - 1121280; }
    dst[i] = f2bf(ldf(s, j, f32));
}

// ------------------------------------------------- all 6 biases -> f32 scratch
__global__ void cvt_bias(const void* s0, const void* s1, const void* s2,
                         const void* s3, const void* s4, const void* s5,
                         float* __restrict__ dst, const int* __restrict__ flag)
{
    const int f32 = *flag;
    int i = blockIdx.x * 256 + threadIdx.x;
    if (i >= 2942) return;
    float v;
    if      (i < 512)  v = ldf(s0, i, f32);
    else if (i < 542)  v = ldf(s1, i - 512, f32);
    else if (i < 1502) v = ldf(s2, i - 542, f32);
    else if (i < 2222) v = ldf(s3, i - 1502, f32);
    else if (i < 2702) v = ldf(s4, i - 2222, f32);
    else               v = ldf(s5, i - 2702, f32);
    dst[i] = v;
}

// ---------------------------------------------------------------- conv GEMM
// Direct-to-VGPR fragments: no LDS, no barriers, no gl2lds. Each MFMA fragment
// is 8 contiguous bf16 at (row, quad*8) -> one global_load_dwordx4. The
// compiler pipelines loads across the fully-unrolled 27-off loop with vmcnt(N).
// kc outer / off inner keeps the 27 shifted B-reads in an L1/L2-resident window.
__global__ __launch_bounds__(256, 3) void conv_gemm(
    const u16* __restrict__ xpad, const u16* __restrict__ wt,
    const float* __restrict__ bconv, u16* __restrict__ y)
{
    const int tid = threadIdx.x;
    const int bx = blockIdx.x;                 // 0..783, XCD-aware remap
    const int ln = (bx & 7) * 98 + (bx >> 3);
    const int m_t = ln / 196;
    const int n_t = ln - m_t * 196;
    const int n_base = n_t * 128;
    const int m_base = m_t * 128;
    const int lane = tid & 63;
    const int wid  = tid >> 6;
    const int quad = lane >> 4;
    const int l16  = lane & 15;
    const int wm = (wid & 1) * 64;
    const int wn = (wid >> 1) * 64;

    // per-lane fragment base pointers
    const u16* aptr[4];
    #pragma unroll
    for (int mi = 0; mi < 4; ++mi)
        aptr[mi] = wt + (long)(m_base + wm + mi * 16 + l16) * 512 + quad * 8;
    const u16* bptr[4];
    #pragma unroll
    for (int ni = 0; ni < 4; ++ni) {
        const int n = n_base + wn + ni * 16 + l16;
        int b = n / 12544, r = n % 12544;
        int t = r / 784,   q = r % 784;
        int h = q / 28,    w = q % 28;
        bptr[ni] = xpad + (long)(((b * 18 + t) * 30 + h) * 30 + w) * 512 + quad * 8;
    }

    f32x4 acc[4][4] = {};

    for (int kc = 0; kc < 16; ++kc) {
        const int kcol = kc * 32;
        #pragma unroll
        for (int kd = 0; kd < 3; ++kd)
        #pragma unroll
        for (int kh = 0; kh < 3; ++kh)
        #pragma unroll
        for (int kw = 0; kw < 3; ++kw) {
            const int off  = (kd * 3 + kh) * 3 + kw;
            const int doff = kd * 900 + kh * 30 + kw;
            bf16x8 af[4], bfr[4];
            #pragma unroll
            for (int mi = 0; mi < 4; ++mi)
                af[mi]  = *(const bf16x8*)(aptr[mi] + off * 262144 + kcol);
            #pragma unroll
            for (int ni = 0; ni < 4; ++ni)
                bfr[ni] = *(const bf16x8*)(bptr[ni] + doff * 512 + kcol);
            #pragma unroll
            for (int mi = 0; mi < 4; ++mi)
                #pragma unroll
                for (int ni = 0; ni < 4; ++ni)
                    acc[mi][ni] = __builtin_amdgcn_mfma_f32_16x16x32_bf16(
                        af[mi], bfr[ni], acc[mi][ni], 0, 0, 0);
        }
    }
    #pragma unroll
    for (int mi = 0; mi < 4; ++mi) {
        const int mrow = m_base + wm + mi * 16 + quad * 4;
        float bias[4];
        #pragma unroll
        for (int r = 0; r < 4; ++r) bias[r] = bconv[mrow + r];
        #pragma unroll
        for (int ni = 0; ni < 4; ++ni) {
            const int ng = n_base + wn + ni * 16 + l16;
            f32x4 a = acc[mi][ni];
            u16 o0 = f2bf(fmaxf(a[0] + bias[0], 0.f));
            u16 o1 = f2bf(fmaxf(a[1] + bias[1], 0.f));
            u16 o2 = f2bf(fmaxf(a[2] + bias[2], 0.f));
            u16 o3 = f2bf(fmaxf(a[3] + bias[3], 0.f));
            uint2 pv;
            pv.x = (u32)o0 | ((u32)o1 << 16);
            pv.y = (u32)o2 | ((u32)o3 << 16);
            *(uint2*)&y[(long)ng * 512 + mrow] = pv;
        }
    }
}

// ---------------------------------------------------------------- pools
__device__ __forceinline__ uint4 max8(uint4 A, uint4 Bv)
{
    const u16* a = (const u16*)&A;
    const u16* b = (const u16*)&Bv;
    uint4 R;
    u16* r = (u16*)&R;
    #pragma unroll
    for (int i = 0; i < 8; ++i) r[i] = (bf2f(a[i]) >= bf2f(b[i])) ? a[i] : b[i];
    return R;
}

__global__ void pool4_kernel(const u16* __restrict__ y, u16* __restrict__ p4)
{
    int g = blockIdx.x * 256 + threadIdx.x;
    if (g >= 2 * 13 * 784 * 64) return;
    const int c8 = g & 63;
    int pos = g >> 6;
    const int hw = pos % 784; pos /= 784;
    const int t0 = pos % 13; const int b = pos / 13;
    const u16* src = y + ((long)((b * 16 + t0) * 784 + hw)) * 512 + c8 * 8;
    uint4 v0 = *(const uint4*)(src);
    uint4 v1 = *(const uint4*)(src + 401408);
    uint4 v2 = *(const uint4*)(src + 802816);
    uint4 v3 = *(const uint4*)(src + 1204224);
    uint4 m = max8(max8(v0, v1), max8(v2, v3));
    *(uint4*)&p4[((long)((b * 13 + t0) * 784 + hw)) * 512 + c8 * 8] = m;
}

__global__ void pools2(const u16* __restrict__ p4, u16* __restrict__ p8,
                       u16* __restrict__ p12, u16* __restrict__ p16)
{
    int g = blockIdx.x * 256 + threadIdx.x;
    if (g >= 1505280) return;
    int Td; u16* dst; int nwin;
    if (g < 903168)       { Td = 9; dst = p8;  nwin = 2; }
    else if (g < 1404928) { g -= 903168;  Td = 5; dst = p12; nwin = 3; }
    else                  { g -= 1404928; Td = 1; dst = p16; nwin = 4; }
    const int c8 = g & 63;
    int pos = g >> 6;
    const int hw = pos % 784; pos /= 784;
    const int t = pos % Td; const int b = pos / Td;
    const u16* src = p4 + ((long)((b * 13 + t) * 784 + hw)) * 512 + c8 * 8;
    uint4 m = *(const uint4*)(src);
    #pragma unroll 3
    for (int j = 1; j < nwin; ++j)
        m = max8(m, *(const uint4*)(src + (long)j * 4 * 784 * 512));
    *(uint4*)&dst[((long)((b * Td + t) * 784 + hw)) * 512 + c8 * 8] = m;
}

// ---------------------------------------------------------------- fused heads GEMM
// BK=64 (8 K-steps), XOR-swizzled LDS staging (kept from R5: saved ~58 us).
__global__ __launch_bounds__(256, 2) void heads_gemm(
    const u16* __restrict__ p16, const u16* __restrict__ p12,
    const u16* __restrict__ p8,  const u16* __restrict__ p4,
    const u16* __restrict__ wcls, const u16* __restrict__ wb1,
    const u16* __restrict__ wb34, const u16* __restrict__ wb2,
    const u16* __restrict__ wb4,  const float* __restrict__ bfs,
    float* __restrict__ clsr, void* __restrict__ outv,
    const int* __restrict__ flag)
{
    const int f32 = *flag;
    int bid = blockIdx.x;
    const u16* pool; const u16* wbp; int Ti, CH, nt, mt; long boff, coff, ooff;
    if (bid < 104)      {             nt = bid % 13;  mt = bid / 13;  pool = p16; wbp = wb1;  Ti = 1;  CH = 960; boff = 542;  coff = 0;      ooff = 1317120; }
    else if (bid < 476) { bid -= 104; nt = bid % 62;  mt = bid / 62;  pool = p12; wbp = wb34; Ti = 5;  CH = 720; boff = 1502; coff = 47040;  ooff = 2822400; }
    else if (bid < 920) { bid -= 476; nt = bid % 111; mt = bid / 111; pool = p8;  wbp = wb2;  Ti = 9;  CH = 480; boff = 2222; coff = 282240; ooff = 8467200; }
    else                { bid -= 920; nt = bid % 160; mt = bid / 160; pool = p4;  wbp = wb4;  Ti = 13; CH = 240; boff = 2702; coff = 705600; ooff = 15240960; }
    const int M = 30 + CH;
    const int THW = Ti * 784;
    const int N = 2 * THW;
    const int n_base = nt * 128;
    const int m_base = mt * 128;

    __shared__ u16 lds_a[128 * 64];
    __shared__ u16 lds_b[128 * 64];
    const int tid = threadIdx.x;
    const int lane = tid & 63;
    const int wid  = tid >> 6;
    const int quad = lane >> 4;
    const int l16  = lane & 15;
    const int wm = (wid & 1) * 64;
    const int wn = (wid >> 1) * 64;
    const int srow = tid >> 3;
    const int lc8  = ((tid & 7) ^ (srow & 7)) * 8;

    const u16* arow[4]; const u16* brow[4];
    #pragma unroll
    for (int j = 0; j < 4; ++j) {
        int m = m_base + j * 32 + srow; if (m > M - 1) m = M - 1;
        arow[j] = ((m < 30) ? (wcls + m * 512) : (wbp + (m - 30) * 512)) + lc8;
        int n = n_base + j * 32 + srow; if (n > N - 1) n = N - 1;
        brow[j] = pool + (long)n * 512 + lc8;
    }

    u16* ldst_a = &lds_a[tid * 8];
    u16* ldst_b = &lds_b[tid * 8];

    int rowA[4], rowB[4];
    #pragma unroll
    for (int i = 0; i < 4; ++i) {
        rowA[i] = (wm + i * 16 + l16) * 64;
        rowB[i] = (wn + i * 16 + l16) * 64;
    }
    const int cx  = l16 & 7;
    const int ch0 = (quad ^ cx) * 8;
    const int ch1 = ((4 + quad) ^ cx) * 8;

    f32x4 acc[4][4] = {};
    for (int kc = 0; kc < 8; ++kc) {
        const int kcol = kc * 64;
        #pragma unroll
        for (int j = 0; j < 4; ++j)
            gl2lds16(arow[j] + kcol, ldst_a + j * 2048);
        #pragma unroll
        for (int j = 0; j < 4; ++j)
            gl2lds16(brow[j] + kcol, ldst_b + j * 2048);
        __syncthreads();
        #pragma unroll
        for (int h = 0; h < 2; ++h) {
            const int co = h ? ch1 : ch0;
            bf16x8 af[4], bfr[4];
            #pragma unroll
            for (int mi = 0; mi < 4; ++mi)
                af[mi]  = *(const bf16x8*)&lds_a[rowA[mi] + co];
            #pragma unroll
            for (int ni = 0; ni < 4; ++ni)
                bfr[ni] = *(const bf16x8*)&lds_b[rowB[ni] + co];
            #pragma unroll
            for (int mi = 0; mi < 4; ++mi)
                #pragma unroll
                for (int ni = 0; ni < 4; ++ni)
                    acc[mi][ni] = __builtin_amdgcn_mfma_f32_16x16x32_bf16(
                        af[mi], bfr[ni], acc[mi][ni], 0, 0, 0);
        }
        __syncthreads();
    }
    const float* bcls = bfs + 512;
    const float* bb   = bfs + boff;
    #pragma unroll
    for (int mi = 0; mi < 4; ++mi) {
        const int mrow = m_base + wm + mi * 16 + quad * 4;
        #pragma unroll
        for (int ni = 0; ni < 4; ++ni) {
            const int ng = n_base + wn + ni * 16 + l16;
            if (ng >= N) continue;
            const int b  = ng / THW;
            const int rr = ng % THW;
            f32x4 a = acc[mi][ni];
            #pragma unroll
            for (int r = 0; r < 4; ++r) {
                const int m = mrow + r;
                if (m >= M) break;
                const float bias = (m < 30) ? bcls[m] : bb[m - 30];
                const float v = a[r] + bias;
                if (m < 30) {
                    clsr[coff + ((long)(b * 30 + m)) * THW + rr] = v;
                } else {
                    const long oi = ooff + ((long)(b * CH + (m - 30))) * THW + rr;
                    if (f32) ((float*)outv)[oi] = v;
                    else     ((u16*)outv)[oi]   = f2bf(v);
                }
            }
        }
    }
}

// ---------------------------------------------------------------- pair softmax
__global__ void softmax_all(const float* __restrict__ clsr,
                            void* __restrict__ outv, const int* __restrict__ flag)
{
    const int f32 = *flag;
    int g = blockIdx.x * 256 + threadIdx.x;
    if (g >= 658560) return;
    int Ti; long off;
    if      (g < 23520)  { Ti = 1;  off = 0; }
    else if (g < 141120) { Ti = 5;  off = 47040;  g -= 23520; }
    else if (g < 352800) { Ti = 9;  off = 282240; g -= 141120; }
    else                 { Ti = 13; off = 705600; g -= 352800; }
    const int THW = Ti * 784;
    const int rr = g % THW;
    int r2 = g / THW;
    const int j = r2 % 15; const int b = r2 / 15;
    const long i0 = off + ((long)(b * 30 + j)) * THW + rr;
    const long i1 = off + ((long)(b * 30 + j + 15)) * THW + rr;
    const float s0 = clsr[i0], s1 = clsr[i1];
    const float mx = fmaxf(s0, s1);
    const float e0 = __expf(s0 - mx), e1 = __expf(s1 - mx);
    const float inv = 1.0f / (e0 + e1);
    if (f32) {
        ((float*)outv)[i0] = e0 * inv;
        ((float*)outv)[i1] = e1 * inv;
    } else {
        ((u16*)outv)[i0] = f2bf(e0 * inv);
        ((u16*)outv)[i1] = f2bf(e1 * inv);
    }
}

// ---------------------------------------------------------------- launcher
extern "C" void kernel_launch(void* const* d_in, const int* in_sizes, int n_in,
                              void* d_out, int out_size, void* d_ws, size_t ws_size,
                              hipStream_t stream)
{
    const void* base_feat = d_in[0];
    const u32*  im_info   = (const u32*)d_in[1];
    const void* W_conv    = d_in[4];
    const void* b_conv    = d_in[5];
    const void* W_cls     = d_in[6];
    const void* b_cls     = d_in[7];
    const void* W_bbox    = d_in[8];
    const void* b_bbox    = d_in[9];
    const void* W_bbox34  = d_in[10];
    const void* b_bbox34  = d_in[11];
    const void* W_bbox2   = d_in[12];
    const void* b_bbox2   = d_in[13];
    const void* W_bbox4   = d_in[14];
    const void* b_bbox4   = d_in[15];

    char* ws = (char*)d_ws;
    u16* xpad = (u16*)(ws + 0);            // 33,177,600 B
    u16* wt   = (u16*)(ws + 33177600);     // 14,155,776 B
    u16* y    = (u16*)(ws + 47333376);     // 25,690,112 B (end 73,023,488)
    u16* p4   = (u16*)(ws + 0);            // phase-2 (xpad/wt dead after conv)
    u16* p8   = (u16*)(ws + 20873216);
    u16* p12  = (u16*)(ws + 35323904);
    u16* p16  = (u16*)(ws + 43352064);
    float* clsr = (float*)(ws + 44957696);
    int*   flag = (int*)(ws + 73023488);
    u16*   whd  = (u16*)(ws + 73023552);
    float* bfs  = (float*)(ws + 75511872);
    u16* w_cls_b  = whd;
    u16* w_b1_b   = whd + 15360;
    u16* w_b34_b  = whd + 506880;
    u16* w_b2_b   = whd + 875520;
    u16* w_b4_b   = whd + 1121280;

    detect_dtype<<<1, 64, 0, stream>>>(im_info, flag);
    zero_kernel<<<8100, 256, 0, stream>>>((uint4*)xpad, 2073600);
    pad_fill<<<7168, 256, 0, stream>>>(base_feat, xpad, flag);
    wt_transform<<<1024, 256, 0, stream>>>(W_conv, wt, flag);
    cvt_heads<<<4860, 256, 0, stream>>>(W_cls, W_bbox, W_bbox34, W_bbox2, W_bbox4,
                                        whd, flag);
    cvt_bias<<<12, 256, 0, stream>>>(b_conv, b_cls, b_bbox, b_bbox34, b_bbox2,
                                     b_bbox4, bfs, flag);

    conv_gemm<<<784, 256, 0, stream>>>(xpad, wt, bfs, y);

    pool4_kernel<<<5096, 256, 0, stream>>>(y, p4);
    pools2<<<5880, 256, 0, stream>>>(p4, p8, p12, p16);

    heads_gemm<<<1400, 256, 0, stream>>>(p16, p12, p8, p4,
                                         w_cls_b, w_b1_b, w_b34_b, w_b2_b, w_b4_b,
                                         bfs, clsr, d_out, flag);

    softmax_all<<<2573, 256, 0, stream>>>(clsr, d_out, flag);
}

// Round 7
// 705.886 us; speedup vs baseline: 4.6412x; 4.6412x over previous
//
#include <hip/hip_runtime.h>

typedef unsigned short u16;
typedef unsigned int   u32;
typedef __bf16  bf16x8 __attribute__((ext_vector_type(8)));
typedef float   f32x4  __attribute__((ext_vector_type(4)));

__device__ __forceinline__ float bf2f(u16 u) {
    u32 v = ((u32)u) << 16;
    return __builtin_bit_cast(float, v);
}
__device__ __forceinline__ u16 f2bf(float f) {
    u32 u = __builtin_bit_cast(u32, f);
    return (u16)((u + 0x7FFFu + ((u >> 16) & 1u)) >> 16);   // RNE
}
__device__ __forceinline__ float ldf(const void* p, long i, int f32) {
    return f32 ? ((const float*)p)[i] : bf2f(((const u16*)p)[i]);
}
// async global->LDS, 16B per lane (LDS dst = wave-uniform base + lane*16)
__device__ __forceinline__ void gl2lds16(const u16* g, u16* l) {
    __builtin_amdgcn_global_load_lds(
        (const __attribute__((address_space(1))) void*)g,
        (__attribute__((address_space(3))) void*)l, 16, 0, 0);
}

// ------------------------------------------------------------- dtype detect
__global__ void detect_dtype(const u32* __restrict__ im, int* __restrict__ flag)
{
    if (blockIdx.x == 0 && threadIdx.x == 0)
        *flag = (im[0] == 0x43E00000u) ? 1 : 0;   // 448.0f fp32 vs packed bf16
}

// ---------------------------------------------------------------- zero (xpad)
__global__ void zero_kernel(uint4* __restrict__ p, const int n)
{
    int i = blockIdx.x * 256 + threadIdx.x;
    if (i < n) p[i] = uint4{0u, 0u, 0u, 0u};
}

// ------------------------------------------------- pad+transpose base_feat
__global__ void pad_fill(const void* __restrict__ src, u16* __restrict__ xpad,
                         const int* __restrict__ flag)
{
    const int f32 = *flag;
    __shared__ u16 lds[56 * 40];
    int blk = blockIdx.x;
    const int h2  = blk % 14;  blk /= 14;
    const int c32 = blk & 15;  blk >>= 4;
    const int t   = blk & 15;
    const int b   = blk >> 4;
    const int tid = threadIdx.x;
    const long sbase = ((long)(b * 512 + c32 * 32) * 16 + t) * 784 + h2 * 56;
    #pragma unroll
    for (int it = tid; it < 1792; it += 256) {
        const int c = it / 56, p = it - c * 56;
        float v = f32 ? ((const float*)src)[sbase + (long)c * 12544 + p]
                      : bf2f(((const u16*)src)[sbase + (long)c * 12544 + p]);
        lds[p * 40 + c] = f2bf(v);
    }
    __syncthreads();
    if (tid < 224) {
        const int p = tid >> 2, g = tid & 3;
        const int h = h2 * 2 + p / 28, w = p % 28;
        const long o = (((long)(b * 18 + t + 1) * 30 + h + 1) * 30 + (w + 1)) * 512
                       + c32 * 32 + g * 8;
        *(uint4*)&xpad[o] = *(const uint4*)&lds[p * 40 + g * 8];
    }
}

// ------------------------------------------------- W_conv [O][I][27] -> Wt[27][O][I]
__global__ void wt_transform(const void* __restrict__ wconv, u16* __restrict__ wt,
                             const int* __restrict__ flag)
{
    const int f32 = *flag;
    __shared__ u16 lds[256 * 28];
    const int tid = threadIdx.x;
    const int pair_base = blockIdx.x * 256;
    const long s0 = (long)pair_base * 27;
    for (int it = tid; it < 256 * 27; it += 256) {
        const int p = it / 27, o = it - p * 27;
        float v = f32 ? ((const float*)wconv)[s0 + it]
                      : bf2f(((const u16*)wconv)[s0 + it]);
        lds[p * 28 + o] = f2bf(v);
    }
    __syncthreads();
    #pragma unroll
    for (int off = 0; off < 27; ++off)
        wt[(long)off * 262144 + pair_base + tid] = lds[tid * 28 + off];
}

// ------------------------------------------------- head weights -> bf16 (merged)
__global__ void cvt_heads(const void* s0, const void* s1, const void* s2,
                          const void* s3, const void* s4,
                          u16* __restrict__ dst, const int* __restrict__ flag)
{
    const int f32 = *flag;
    int i = blockIdx.x * 256 + threadIdx.x;
    if (i >= 1244160) return;
    const void* s; long j;
    if      (i < 15360)   { s = s0; j = i; }
    else if (i < 506880)  { s = s1; j = i - 15360; }
    else if (i < 875520)  { s = s2; j = i - 506880; }
    else if (i < 1121280) { s = s3; j = i - 875520; }
    else                  { s = s4; j = i - 1121280; }
    dst[i] = f2bf(ldf(s, j, f32));
}

// ------------------------------------------------- all 6 biases -> f32 scratch
__global__ void cvt_bias(const void* s0, const void* s1, const void* s2,
                         const void* s3, const void* s4, const void* s5,
                         float* __restrict__ dst, const int* __restrict__ flag)
{
    const int f32 = *flag;
    int i = blockIdx.x * 256 + threadIdx.x;
    if (i >= 2942) return;
    float v;
    if      (i < 512)  v = ldf(s0, i, f32);
    else if (i < 542)  v = ldf(s1, i - 512, f32);
    else if (i < 1502) v = ldf(s2, i - 542, f32);
    else if (i < 2222) v = ldf(s3, i - 1502, f32);
    else if (i < 2702) v = ldf(s4, i - 2222, f32);
    else               v = ldf(s5, i - 2702, f32);
    dst[i] = v;
}

// ---------------------------------------------------------------- conv GEMM (R4)
// 128x128, BK=32, XOR-swizzled LDS, kc outer / off inner. Fallback path.
__global__ __launch_bounds__(256, 2) void conv_gemm(
    const u16* __restrict__ xpad, const u16* __restrict__ wt,
    const float* __restrict__ bconv, u16* __restrict__ y)
{
    __shared__ u16 lds_a[128 * 32];
    __shared__ u16 lds_b[128 * 32];
    const int tid = threadIdx.x;
    const int bx = blockIdx.x;                 // 0..783, XCD-aware remap
    const int ln = (bx & 7) * 98 + (bx >> 3);
    const int m_t = ln / 196;
    const int n_t = ln - m_t * 196;
    const int n_base = n_t * 128;
    const int m_base = m_t * 128;
    const int lane = tid & 63;
    const int wid  = tid >> 6;
    const int quad = lane >> 4;
    const int l16  = lane & 15;
    const int wm = (wid & 1) * 64;
    const int wn = (wid >> 1) * 64;
    const int sv = tid >> 2;
    const int kk = (((tid & 3) ^ ((tid >> 3) & 3))) * 8;

    const int ng0 = n_base + sv;
    const int ng1 = ng0 + 64;
    int b0 = ng0 / 12544, r0 = ng0 % 12544;
    int t0 = r0 / 784,    q0 = r0 % 784;
    int h0 = q0 / 28,     w0 = q0 % 28;
    int b1 = ng1 / 12544, r1 = ng1 % 12544;
    int t1 = r1 / 784,    q1 = r1 % 784;
    int h1 = q1 / 28,     w1 = q1 % 28;
    const int sa0 = ((b0 * 18 + t0) * 30 + h0) * 30 + w0;
    const int sa1 = ((b1 * 18 + t1) * 30 + h1) * 30 + w1;

    u16* la0 = &lds_a[tid * 8];
    u16* la1 = &lds_a[2048 + tid * 8];
    u16* lb0 = &lds_b[tid * 8];
    u16* lb1 = &lds_b[2048 + tid * 8];

    const u16* aB  = wt + (m_base + sv) * 512 + kk;
    const u16* bB0 = xpad + (long)sa0 * 512 + kk;
    const u16* bB1 = xpad + (long)sa1 * 512 + kk;

    int adA[4], adB[4];
    #pragma unroll
    for (int i = 0; i < 4; ++i) {
        const int ra = wm + i * 16 + l16;
        const int rb = wn + i * 16 + l16;
        adA[i] = ra * 32 + (quad ^ ((ra >> 1) & 3)) * 8;
        adB[i] = rb * 32 + (quad ^ ((rb >> 1) & 3)) * 8;
    }

    f32x4 acc[4][4] = {};

    for (int kc = 0; kc < 16; ++kc) {
        const u16* aK  = aB  + kc * 32;
        const u16* b0K = bB0 + kc * 32;
        const u16* b1K = bB1 + kc * 32;
        #pragma unroll
        for (int kd = 0; kd < 3; ++kd)
        #pragma unroll
        for (int kh = 0; kh < 3; ++kh)
        #pragma unroll
        for (int kw = 0; kw < 3; ++kw) {
            const int off  = (kd * 3 + kh) * 3 + kw;
            const int doff = kd * 900 + kh * 30 + kw;
            gl2lds16(aK + off * 262144, la0);
            gl2lds16(aK + off * 262144 + 64 * 512, la1);
            gl2lds16(b0K + doff * 512, lb0);
            gl2lds16(b1K + doff * 512, lb1);
            __syncthreads();
            bf16x8 af[4], bfr[4];
            #pragma unroll
            for (int mi = 0; mi < 4; ++mi) af[mi]  = *(const bf16x8*)&lds_a[adA[mi]];
            #pragma unroll
            for (int ni = 0; ni < 4; ++ni) bfr[ni] = *(const bf16x8*)&lds_b[adB[ni]];
            #pragma unroll
            for (int mi = 0; mi < 4; ++mi)
                #pragma unroll
                for (int ni = 0; ni < 4; ++ni)
                    acc[mi][ni] = __builtin_amdgcn_mfma_f32_16x16x32_bf16(
                        af[mi], bfr[ni], acc[mi][ni], 0, 0, 0);
            __syncthreads();
        }
    }
    #pragma unroll
    for (int mi = 0; mi < 4; ++mi) {
        const int mrow = m_base + wm + mi * 16 + quad * 4;
        float bias[4];
        #pragma unroll
        for (int r = 0; r < 4; ++r) bias[r] = bconv[mrow + r];
        #pragma unroll
        for (int ni = 0; ni < 4; ++ni) {
            const int ng = n_base + wn + ni * 16 + l16;
            f32x4 a = acc[mi][ni];
            u16 o0 = f2bf(fmaxf(a[0] + bias[0], 0.f));
            u16 o1 = f2bf(fmaxf(a[1] + bias[1], 0.f));
            u16 o2 = f2bf(fmaxf(a[2] + bias[2], 0.f));
            u16 o3 = f2bf(fmaxf(a[3] + bias[3], 0.f));
            uint2 pv;
            pv.x = (u32)o0 | ((u32)o1 << 16);
            pv.y = (u32)o2 | ((u32)o3 << 16);
            *(uint2*)&y[(long)ng * 512 + mrow] = pv;
        }
    }
}

// ------------------------------------------- conv GEMM, split-K x3 (partials)
// Same structure as conv_gemm; each block does one kd-plane (9 taps), writes
// f32 partials (no bias/relu). Grid 2352 -> ~8 resident blocks/CU.
__global__ __launch_bounds__(256, 2) void conv_gemm_sk(
    const u16* __restrict__ xpad, const u16* __restrict__ wt,
    float* __restrict__ ypart)
{
    __shared__ u16 lds_a[128 * 32];
    __shared__ u16 lds_b[128 * 32];
    const int tid = threadIdx.x;
    const int bx = blockIdx.x;                 // 0..2351
    const int ln = (bx & 7) * 294 + (bx >> 3);
    const int split = ln / 784;
    const int tile  = ln - split * 784;
    const int m_t = tile / 196;
    const int n_t = tile - m_t * 196;
    const int n_base = n_t * 128;
    const int m_base = m_t * 128;
    const int lane = tid & 63;
    const int wid  = tid >> 6;
    const int quad = lane >> 4;
    const int l16  = lane & 15;
    const int wm = (wid & 1) * 64;
    const int wn = (wid >> 1) * 64;
    const int sv = tid >> 2;
    const int kk = (((tid & 3) ^ ((tid >> 3) & 3))) * 8;

    const int ng0 = n_base + sv;
    const int ng1 = ng0 + 64;
    int b0 = ng0 / 12544, r0 = ng0 % 12544;
    int t0 = r0 / 784,    q0 = r0 % 784;
    int h0 = q0 / 28,     w0 = q0 % 28;
    int b1 = ng1 / 12544, r1 = ng1 % 12544;
    int t1 = r1 / 784,    q1 = r1 % 784;
    int h1 = q1 / 28,     w1 = q1 % 28;
    const int sa0 = ((b0 * 18 + t0) * 30 + h0) * 30 + w0;
    const int sa1 = ((b1 * 18 + t1) * 30 + h1) * 30 + w1;

    u16* la0 = &lds_a[tid * 8];
    u16* la1 = &lds_a[2048 + tid * 8];
    u16* lb0 = &lds_b[tid * 8];
    u16* lb1 = &lds_b[2048 + tid * 8];

    const u16* aB  = wt + (long)(split * 9) * 262144 + (m_base + sv) * 512 + kk;
    const u16* bB0 = xpad + (long)(sa0 + split * 900) * 512 + kk;
    const u16* bB1 = xpad + (long)(sa1 + split * 900) * 512 + kk;

    int adA[4], adB[4];
    #pragma unroll
    for (int i = 0; i < 4; ++i) {
        const int ra = wm + i * 16 + l16;
        const int rb = wn + i * 16 + l16;
        adA[i] = ra * 32 + (quad ^ ((ra >> 1) & 3)) * 8;
        adB[i] = rb * 32 + (quad ^ ((rb >> 1) & 3)) * 8;
    }

    f32x4 acc[4][4] = {};

    for (int kc = 0; kc < 16; ++kc) {
        const u16* aK  = aB  + kc * 32;
        const u16* b0K = bB0 + kc * 32;
        const u16* b1K = bB1 + kc * 32;
        #pragma unroll
        for (int kh = 0; kh < 3; ++kh)
        #pragma unroll
        for (int kw = 0; kw < 3; ++kw) {
            const int off  = kh * 3 + kw;
            const int doff = kh * 30 + kw;
            gl2lds16(aK + off * 262144, la0);
            gl2lds16(aK + off * 262144 + 64 * 512, la1);
            gl2lds16(b0K + doff * 512, lb0);
            gl2lds16(b1K + doff * 512, lb1);
            __syncthreads();
            bf16x8 af[4], bfr[4];
            #pragma unroll
            for (int mi = 0; mi < 4; ++mi) af[mi]  = *(const bf16x8*)&lds_a[adA[mi]];
            #pragma unroll
            for (int ni = 0; ni < 4; ++ni) bfr[ni] = *(const bf16x8*)&lds_b[adB[ni]];
            #pragma unroll
            for (int mi = 0; mi < 4; ++mi)
                #pragma unroll
                for (int ni = 0; ni < 4; ++ni)
                    acc[mi][ni] = __builtin_amdgcn_mfma_f32_16x16x32_bf16(
                        af[mi], bfr[ni], acc[mi][ni], 0, 0, 0);
            __syncthreads();
        }
    }
    float* yp = ypart + (long)split * 12845056;
    #pragma unroll
    for (int mi = 0; mi < 4; ++mi) {
        const int mrow = m_base + wm + mi * 16 + quad * 4;
        #pragma unroll
        for (int ni = 0; ni < 4; ++ni) {
            const int ng = n_base + wn + ni * 16 + l16;
            *(f32x4*)&yp[(long)ng * 512 + mrow] = acc[mi][ni];
        }
    }
}

// ------------------------------------------- reduce partials + bias + relu
__global__ void reduce_y(const float* __restrict__ p0, const float* __restrict__ p1,
                         const float* __restrict__ p2, const float* __restrict__ bfs,
                         u16* __restrict__ y)
{
    int g = blockIdx.x * 256 + threadIdx.x;
    if (g >= 3211264) return;
    const long i = (long)g * 4;
    f32x4 a = *(const f32x4*)(p0 + i);
    f32x4 b = *(const f32x4*)(p1 + i);
    f32x4 c = *(const f32x4*)(p2 + i);
    const int m = (int)(i & 511);
    f32x4 bi = *(const f32x4*)(bfs + m);
    uint2 pv;
    u16 o0 = f2bf(fmaxf(a[0] + b[0] + c[0] + bi[0], 0.f));
    u16 o1 = f2bf(fmaxf(a[1] + b[1] + c[1] + bi[1], 0.f));
    u16 o2 = f2bf(fmaxf(a[2] + b[2] + c[2] + bi[2], 0.f));
    u16 o3 = f2bf(fmaxf(a[3] + b[3] + c[3] + bi[3], 0.f));
    pv.x = (u32)o0 | ((u32)o1 << 16);
    pv.y = (u32)o2 | ((u32)o3 << 16);
    *(uint2*)&y[i] = pv;
}

// ---------------------------------------------------------------- pools
__device__ __forceinline__ uint4 max8(uint4 A, uint4 Bv)
{
    const u16* a = (const u16*)&A;
    const u16* b = (const u16*)&Bv;
    uint4 R;
    u16* r = (u16*)&R;
    #pragma unroll
    for (int i = 0; i < 8; ++i) r[i] = (bf2f(a[i]) >= bf2f(b[i])) ? a[i] : b[i];
    return R;
}

__global__ void pool4_kernel(const u16* __restrict__ y, u16* __restrict__ p4)
{
    int g = blockIdx.x * 256 + threadIdx.x;
    if (g >= 2 * 13 * 784 * 64) return;
    const int c8 = g & 63;
    int pos = g >> 6;
    const int hw = pos % 784; pos /= 784;
    const int t0 = pos % 13; const int b = pos / 13;
    const u16* src = y + ((long)((b * 16 + t0) * 784 + hw)) * 512 + c8 * 8;
    uint4 v0 = *(const uint4*)(src);
    uint4 v1 = *(const uint4*)(src + 401408);
    uint4 v2 = *(const uint4*)(src + 802816);
    uint4 v3 = *(const uint4*)(src + 1204224);
    uint4 m = max8(max8(v0, v1), max8(v2, v3));
    *(uint4*)&p4[((long)((b * 13 + t0) * 784 + hw)) * 512 + c8 * 8] = m;
}

__global__ void pools2(const u16* __restrict__ p4, u16* __restrict__ p8,
                       u16* __restrict__ p12, u16* __restrict__ p16)
{
    int g = blockIdx.x * 256 + threadIdx.x;
    if (g >= 1505280) return;
    int Td; u16* dst; int nwin;
    if (g < 903168)       { Td = 9; dst = p8;  nwin = 2; }
    else if (g < 1404928) { g -= 903168;  Td = 5; dst = p12; nwin = 3; }
    else                  { g -= 1404928; Td = 1; dst = p16; nwin = 4; }
    const int c8 = g & 63;
    int pos = g >> 6;
    const int hw = pos % 784; pos /= 784;
    const int t = pos % Td; const int b = pos / Td;
    const u16* src = p4 + ((long)((b * 13 + t) * 784 + hw)) * 512 + c8 * 8;
    uint4 m = *(const uint4*)(src);
    #pragma unroll 3
    for (int j = 1; j < nwin; ++j)
        m = max8(m, *(const uint4*)(src + (long)j * 4 * 784 * 512));
    *(uint4*)&dst[((long)((b * Td + t) * 784 + hw)) * 512 + c8 * 8] = m;
}

// ---------------------------------------------------------------- fused heads GEMM
// BK=64 (8 K-steps), XOR-swizzled LDS staging.
__global__ __launch_bounds__(256, 2) void heads_gemm(
    const u16* __restrict__ p16, const u16* __restrict__ p12,
    const u16* __restrict__ p8,  const u16* __restrict__ p4,
    const u16* __restrict__ wcls, const u16* __restrict__ wb1,
    const u16* __restrict__ wb34, const u16* __restrict__ wb2,
    const u16* __restrict__ wb4,  const float* __restrict__ bfs,
    float* __restrict__ clsr, void* __restrict__ outv,
    const int* __restrict__ flag)
{
    const int f32 = *flag;
    int bid = blockIdx.x;
    const u16* pool; const u16* wbp; int Ti, CH, nt, mt; long boff, coff, ooff;
    if (bid < 104)      {             nt = bid % 13;  mt = bid / 13;  pool = p16; wbp = wb1;  Ti = 1;  CH = 960; boff = 542;  coff = 0;      ooff = 1317120; }
    else if (bid < 476) { bid -= 104; nt = bid % 62;  mt = bid / 62;  pool = p12; wbp = wb34; Ti = 5;  CH = 720; boff = 1502; coff = 47040;  ooff = 2822400; }
    else if (bid < 920) { bid -= 476; nt = bid % 111; mt = bid / 111; pool = p8;  wbp = wb2;  Ti = 9;  CH = 480; boff = 2222; coff = 282240; ooff = 8467200; }
    else                { bid -= 920; nt = bid % 160; mt = bid / 160; pool = p4;  wbp = wb4;  Ti = 13; CH = 240; boff = 2702; coff = 705600; ooff = 15240960; }
    const int M = 30 + CH;
    const int THW = Ti * 784;
    const int N = 2 * THW;
    const int n_base = nt * 128;
    const int m_base = mt * 128;

    __shared__ u16 lds_a[128 * 64];
    __shared__ u16 lds_b[128 * 64];
    const int tid = threadIdx.x;
    const int lane = tid & 63;
    const int wid  = tid >> 6;
    const int quad = lane >> 4;
    const int l16  = lane & 15;
    const int wm = (wid & 1) * 64;
    const int wn = (wid >> 1) * 64;
    const int srow = tid >> 3;
    const int lc8  = ((tid & 7) ^ (srow & 7)) * 8;

    const u16* arow[4]; const u16* brow[4];
    #pragma unroll
    for (int j = 0; j < 4; ++j) {
        int m = m_base + j * 32 + srow; if (m > M - 1) m = M - 1;
        arow[j] = ((m < 30) ? (wcls + m * 512) : (wbp + (m - 30) * 512)) + lc8;
        int n = n_base + j * 32 + srow; if (n > N - 1) n = N - 1;
        brow[j] = pool + (long)n * 512 + lc8;
    }

    u16* ldst_a = &lds_a[tid * 8];
    u16* ldst_b = &lds_b[tid * 8];

    int rowA[4], rowB[4];
    #pragma unroll
    for (int i = 0; i < 4; ++i) {
        rowA[i] = (wm + i * 16 + l16) * 64;
        rowB[i] = (wn + i * 16 + l16) * 64;
    }
    const int cx  = l16 & 7;
    const int ch0 = (quad ^ cx) * 8;
    const int ch1 = ((4 + quad) ^ cx) * 8;

    f32x4 acc[4][4] = {};
    for (int kc = 0; kc < 8; ++kc) {
        const int kcol = kc * 64;
        #pragma unroll
        for (int j = 0; j < 4; ++j)
            gl2lds16(arow[j] + kcol, ldst_a + j * 2048);
        #pragma unroll
        for (int j = 0; j < 4; ++j)
            gl2lds16(brow[j] + kcol, ldst_b + j * 2048);
        __syncthreads();
        #pragma unroll
        for (int h = 0; h < 2; ++h) {
            const int co = h ? ch1 : ch0;
            bf16x8 af[4], bfr[4];
            #pragma unroll
            for (int mi = 0; mi < 4; ++mi)
                af[mi]  = *(const bf16x8*)&lds_a[rowA[mi] + co];
            #pragma unroll
            for (int ni = 0; ni < 4; ++ni)
                bfr[ni] = *(const bf16x8*)&lds_b[rowB[ni] + co];
            #pragma unroll
            for (int mi = 0; mi < 4; ++mi)
                #pragma unroll
                for (int ni = 0; ni < 4; ++ni)
                    acc[mi][ni] = __builtin_amdgcn_mfma_f32_16x16x32_bf16(
                        af[mi], bfr[ni], acc[mi][ni], 0, 0, 0);
        }
        __syncthreads();
    }
    const float* bcls = bfs + 512;
    const float* bb   = bfs + boff;
    #pragma unroll
    for (int mi = 0; mi < 4; ++mi) {
        const int mrow = m_base + wm + mi * 16 + quad * 4;
        #pragma unroll
        for (int ni = 0; ni < 4; ++ni) {
            const int ng = n_base + wn + ni * 16 + l16;
            if (ng >= N) continue;
            const int b  = ng / THW;
            const int rr = ng % THW;
            f32x4 a = acc[mi][ni];
            #pragma unroll
            for (int r = 0; r < 4; ++r) {
                const int m = mrow + r;
                if (m >= M) break;
                const float bias = (m < 30) ? bcls[m] : bb[m - 30];
                const float v = a[r] + bias;
                if (m < 30) {
                    clsr[coff + ((long)(b * 30 + m)) * THW + rr] = v;
                } else {
                    const long oi = ooff + ((long)(b * CH + (m - 30))) * THW + rr;
                    if (f32) ((float*)outv)[oi] = v;
                    else     ((u16*)outv)[oi]   = f2bf(v);
                }
            }
        }
    }
}

// ---------------------------------------------------------------- pair softmax
__global__ void softmax_all(const float* __restrict__ clsr,
                            void* __restrict__ outv, const int* __restrict__ flag)
{
    const int f32 = *flag;
    int g = blockIdx.x * 256 + threadIdx.x;
    if (g >= 658560) return;
    int Ti; long off;
    if      (g < 23520)  { Ti = 1;  off = 0; }
    else if (g < 141120) { Ti = 5;  off = 47040;  g -= 23520; }
    else if (g < 352800) { Ti = 9;  off = 282240; g -= 141120; }
    else                 { Ti = 13; off = 705600; g -= 352800; }
    const int THW = Ti * 784;
    const int rr = g % THW;
    int r2 = g / THW;
    const int j = r2 % 15; const int b = r2 / 15;
    const long i0 = off + ((long)(b * 30 + j)) * THW + rr;
    const long i1 = off + ((long)(b * 30 + j + 15)) * THW + rr;
    const float s0 = clsr[i0], s1 = clsr[i1];
    const float mx = fmaxf(s0, s1);
    const float e0 = __expf(s0 - mx), e1 = __expf(s1 - mx);
    const float inv = 1.0f / (e0 + e1);
    if (f32) {
        ((float*)outv)[i0] = e0 * inv;
        ((float*)outv)[i1] = e1 * inv;
    } else {
        ((u16*)outv)[i0] = f2bf(e0 * inv);
        ((u16*)outv)[i1] = f2bf(e1 * inv);
    }
}

// ---------------------------------------------------------------- launcher
extern "C" void kernel_launch(void* const* d_in, const int* in_sizes, int n_in,
                              void* d_out, int out_size, void* d_ws, size_t ws_size,
                              hipStream_t stream)
{
    const void* base_feat = d_in[0];
    const u32*  im_info   = (const u32*)d_in[1];
    const void* W_conv    = d_in[4];
    const void* b_conv    = d_in[5];
    const void* W_cls     = d_in[6];
    const void* b_cls     = d_in[7];
    const void* W_bbox    = d_in[8];
    const void* b_bbox    = d_in[9];
    const void* W_bbox34  = d_in[10];
    const void* b_bbox34  = d_in[11];
    const void* W_bbox2   = d_in[12];
    const void* b_bbox2   = d_in[13];
    const void* W_bbox4   = d_in[14];
    const void* b_bbox4   = d_in[15];

    char* ws = (char*)d_ws;
    const bool splitk = (ws_size >= 206000000ull);

    u16* xpad = (u16*)(ws + 0);            // 33,177,600 B (both paths)
    u16* wt   = (u16*)(ws + 33177600);     // 14,155,776 B (both paths)

    u16 *y, *p4, *p8, *p12, *p16;
    float *clsr, *ypart = nullptr;
    int* flag; u16* whd; float* bfs;

    if (splitk) {
        ypart = (float*)(ws + 47333376);   // 3 x 51,380,224 B -> ends 201,474,048
        flag  = (int*)(ws + 201474048);
        whd   = (u16*)(ws + 201474112);    // 2,488,320 B
        bfs   = (float*)(ws + 203962432);  // 11,768 B -> ends 203,974,200
        // phase-2: xpad/wt/ypart dead in stages
        y    = (u16*)(ws + 0);             // 25,690,112 (over dead xpad)
        p4   = (u16*)(ws + 25690112);      // 20,873,216 -> 46,563,328
        p8   = (u16*)(ws + 46563328);      // 14,450,688 -> 61,014,016
        p12  = (u16*)(ws + 61014016);      //  8,028,160 -> 69,042,176
        p16  = (u16*)(ws + 69042176);      //  1,605,632 -> 70,647,808
        clsr = (float*)(ws + 70647808);    //  5,268,480 -> 75,916,288 (< ypart1)
    } else {
        y    = (u16*)(ws + 47333376);      // 25,690,112 -> 73,023,488
        p4   = (u16*)(ws + 0);
        p8   = (u16*)(ws + 20873216);
        p12  = (u16*)(ws + 35323904);
        p16  = (u16*)(ws + 43352064);
        clsr = (float*)(ws + 44957696);
        flag = (int*)(ws + 73023488);
        whd  = (u16*)(ws + 73023552);
        bfs  = (float*)(ws + 75511872);
    }
    u16* w_cls_b  = whd;
    u16* w_b1_b   = whd + 15360;
    u16* w_b34_b  = whd + 506880;
    u16* w_b2_b   = whd + 875520;
    u16* w_b4_b   = whd + 1121280;

    detect_dtype<<<1, 64, 0, stream>>>(im_info, flag);
    zero_kernel<<<8100, 256, 0, stream>>>((uint4*)xpad, 2073600);
    pad_fill<<<7168, 256, 0, stream>>>(base_feat, xpad, flag);
    wt_transform<<<1024, 256, 0, stream>>>(W_conv, wt, flag);
    cvt_heads<<<4860, 256, 0, stream>>>(W_cls, W_bbox, W_bbox34, W_bbox2, W_bbox4,
                                        whd, flag);
    cvt_bias<<<12, 256, 0, stream>>>(b_conv, b_cls, b_bbox, b_bbox34, b_bbox2,
                                     b_bbox4, bfs, flag);

    if (splitk) {
        conv_gemm_sk<<<2352, 256, 0, stream>>>(xpad, wt, ypart);
        reduce_y<<<12544, 256, 0, stream>>>(ypart, ypart + 12845056,
                                            ypart + 25690112, bfs, y);
    } else {
        conv_gemm<<<784, 256, 0, stream>>>(xpad, wt, bfs, y);
    }

    pool4_kernel<<<5096, 256, 0, stream>>>(y, p4);
    pools2<<<5880, 256, 0, stream>>>(p4, p8, p12, p16);

    heads_gemm<<<1400, 256, 0, stream>>>(p16, p12, p8, p4,
                                         w_cls_b, w_b1_b, w_b34_b, w_b2_b, w_b4_b,
                                         bfs, clsr, d_out, flag);

    softmax_all<<<2573, 256, 0, stream>>>(clsr, d_out, flag);
}